// Round 8
// baseline (229.569 us; speedup 1.0000x reference)
//
#include <hip/hip_runtime.h>

#define TT 2048
#define CC 1024

typedef __attribute__((ext_vector_type(8))) __bf16 bf16x8;
typedef __attribute__((ext_vector_type(4))) float f32x4;
typedef unsigned int u32;
typedef __attribute__((ext_vector_type(2))) u32 u32x2;

__device__ __forceinline__ short f2bf(float f) {
  u32 u = __float_as_uint(f);
  u += 0x7fffu + ((u >> 16) & 1u);  // RTNE
  return (short)(u >> 16);
}

#if __has_builtin(__builtin_amdgcn_cvt_pk_bf16_f32)
__device__ __forceinline__ u32 pack2(float a, float b) {
  auto v = __builtin_amdgcn_cvt_pk_bf16_f32(a, b);
  return __builtin_bit_cast(u32, v);
}
#else
__device__ __forceinline__ u32 pack2(float a, float b) {
  u32 ua = __float_as_uint(a), ub = __float_as_uint(b);
  ua += 0x7fffu + ((ua >> 16) & 1u);
  ub += 0x7fffu + ((ub >> 16) & 1u);
  return (ua >> 16) | (ub & 0xffff0000u);
}
#endif

// ---------------- fused fp32 -> bf16 cast (x | wqkv(Q scaled) | wout) ---------
__global__ __launch_bounds__(256) void cvt_all(const float* __restrict__ x,
                                               const float* __restrict__ wqkv,
                                               const float* __restrict__ wout,
                                               short* __restrict__ dst) {
  int i = blockIdx.x * blockDim.x + threadIdx.x;  // float4 index, < 3145728
  const float* src;
  float sc = 1.0f;
  if (i < 2097152) {
    src = x + (size_t)i * 4;
  } else if (i < 2883584) {
    int j = i - 2097152;
    src = wqkv + (size_t)j * 4;
    if (j < 262144) sc = 0.125f;  // Q block: fold attention scale (exact pow2)
  } else {
    src = wout + (size_t)(i - 2883584) * 4;
  }
  float4 f = *reinterpret_cast<const float4*>(src);
  short4 s;
  s.x = f2bf(f.x * sc); s.y = f2bf(f.y * sc); s.z = f2bf(f.z * sc); s.w = f2bf(f.w * sc);
  reinterpret_cast<short4*>(dst)[i] = s;
}

__device__ __forceinline__ void storev(float* p, float v) { *p = v; }
__device__ __forceinline__ void storev(short* p, float v) { *p = f2bf(v); }

#if __has_builtin(__builtin_amdgcn_global_load_lds)
#define HAVE_GLD_LDS 1
__device__ __forceinline__ void gld_lds16(const short* g, short* l) {
  __builtin_amdgcn_global_load_lds((const __attribute__((address_space(1))) u32*)g,
                                   (__attribute__((address_space(3))) u32*)l, 16, 0, 0);
}
#endif

__device__ __forceinline__ f32x4 mfma16(bf16x8 a, bf16x8 b, f32x4 c) {
  return __builtin_amdgcn_mfma_f32_16x16x32_bf16(a, b, c, 0, 0, 0);
}

template <int NN>
__device__ __forceinline__ void waitvm() {
  if constexpr (NN == 0) asm volatile("s_waitcnt vmcnt(0)" ::: "memory");
  else if constexpr (NN == 3) asm volatile("s_waitcnt vmcnt(3)" ::: "memory");
  else if constexpr (NN == 4) asm volatile("s_waitcnt vmcnt(4)" ::: "memory");
  else if constexpr (NN == 6) asm volatile("s_waitcnt vmcnt(6)" ::: "memory");
  else if constexpr (NN == 8) asm volatile("s_waitcnt vmcnt(8)" ::: "memory");
}

// =================== C[M,N] = A[M,K] * B[N,K]^T, 128xBN 4-phase ===============
// (unchanged from round 4 — see comments there)
#define GNOOP ((void)0)
#define GPHASE4(DB, KS, STG, SYNC)                         \
  {                                                        \
    bf16x8 af[MFRAG], bfr[NFR];                            \
    ldA(af, DB, KS);                                       \
    ldB(bfr, DB, KS);                                      \
    STG;                                                   \
    __builtin_amdgcn_s_setprio(1);                         \
    mmaAll(af, bfr);                                       \
    __builtin_amdgcn_s_setprio(0);                         \
    asm volatile("s_waitcnt lgkmcnt(0)" ::: "memory");     \
    SYNC;                                                  \
    __builtin_amdgcn_s_barrier();                          \
  }

template <typename OutT, int N, int K, int BM, int BN>
__global__ __launch_bounds__(512, 2) void gemm4p(const short* __restrict__ A,
                                                 const short* __restrict__ B,
                                                 OutT* __restrict__ Cm) {
  constexpr int MFRAG = BM / 32;
  constexpr int NFR = BN / 64;
  constexpr int AGLD = BM / 128;
  constexpr int BGLD = BN / 128;
  constexpr int GPP = AGLD + BGLD;
  constexpr int SYNCN = 2 * GPP;
  constexpr int NT = K / 64, NITER = NT / 2;
  constexpr int DBS = 64 * (BM + BN);
  constexpr int TMX = (8192 / BM) / 8;
  extern __shared__ short lds[];
  const int tid = threadIdx.x;
  const int wave = tid >> 6, lane = tid & 63;
  const int quad = lane >> 4, nl = lane & 15;
  const int wm = wave >> 2, wn = wave & 3;

  const int id = blockIdx.x;
  const int xcd = id & 7, slot = id >> 3;
  const int mt = xcd * TMX + (slot % TMX);
  const int nt = slot / TMX;
  const int m0 = mt * BM, n0 = nt * BN;

  const int srow = lane >> 2;
  const int sperm = ((lane & 3) ^ ((lane >> 3) & 3)) * 8;
  const short* pA = A + (size_t)(m0 + wave * (BM / 8) + srow) * K + sperm;
  const short* pB = B + (size_t)(n0 + wave * (BN / 8) + srow) * K + sperm;

  const int perm = (quad ^ ((nl >> 1) & 3)) * 8;

  f32x4 acc[MFRAG][NFR] = {};

  auto stageA = [&](int db, int ks, int t) {
    const short* s = pA + (size_t)t * 64 + ks * 32;
    short* d = lds + db * DBS + ks * (BM * 32) + wave * (BM * 4);
#pragma unroll
    for (int j = 0; j < AGLD; ++j) {
#if HAVE_GLD_LDS
      gld_lds16(s + (size_t)j * 16 * K, d + j * 512);
#else
      *reinterpret_cast<uint4*>(d + j * 512 + lane * 8) =
          *reinterpret_cast<const uint4*>(s + (size_t)j * 16 * K);
#endif
    }
  };
  auto stageB = [&](int db, int ks, int t) {
    const short* s = pB + (size_t)t * 64 + ks * 32;
    short* d = lds + db * DBS + BM * 64 + ks * (BN * 32) + wave * (BN * 4);
#pragma unroll
    for (int j = 0; j < BGLD; ++j) {
#if HAVE_GLD_LDS
      gld_lds16(s + (size_t)j * 16 * K, d + j * 512);
#else
      *reinterpret_cast<uint4*>(d + j * 512 + lane * 8) =
          *reinterpret_cast<const uint4*>(s + (size_t)j * 16 * K);
#endif
    }
  };
  auto stage = [&](int db, int ks, int t) { stageA(db, ks, t); stageB(db, ks, t); };

  auto ldA = [&](bf16x8 (&af)[MFRAG], int db, int ks) {
#pragma unroll
    for (int mf = 0; mf < MFRAG; ++mf)
      af[mf] = *reinterpret_cast<const bf16x8*>(
          &lds[db * DBS + ks * (BM * 32) + (wm * (BM / 2) + mf * 16 + nl) * 32 + perm]);
  };
  auto ldB = [&](bf16x8 (&bfr)[NFR], int db, int ks) {
#pragma unroll
    for (int nf = 0; nf < NFR; ++nf)
      bfr[nf] = *reinterpret_cast<const bf16x8*>(
          &lds[db * DBS + BM * 64 + ks * (BN * 32) + (wn * (BN / 4) + nf * 16 + nl) * 32 + perm]);
  };
  auto mmaAll = [&](const bf16x8 (&af)[MFRAG], const bf16x8 (&bfr)[NFR]) {
#pragma unroll
    for (int mf = 0; mf < MFRAG; ++mf)
#pragma unroll
      for (int nf = 0; nf < NFR; ++nf)
        acc[mf][nf] = mfma16(af[mf], bfr[nf], acc[mf][nf]);
  };

  stage(0, 0, 0); stage(0, 1, 0); stage(1, 0, 1);
  waitvm<SYNCN>();
  __builtin_amdgcn_s_barrier();

  for (int i = 0; i < NITER - 1; ++i) {
    GPHASE4(0, 0, stage(1, 1, 2 * i + 1), waitvm<SYNCN>())
    GPHASE4(0, 1, stage(0, 0, 2 * i + 2), waitvm<SYNCN>())
    GPHASE4(1, 0, stage(0, 1, 2 * i + 2), waitvm<SYNCN>())
    GPHASE4(1, 1, stage(1, 0, 2 * i + 3), waitvm<SYNCN>())
  }
  GPHASE4(0, 0, stage(1, 1, NT - 1), waitvm<SYNCN>())
  GPHASE4(0, 1, GNOOP, waitvm<GPP>())
  GPHASE4(1, 0, GNOOP, waitvm<0>())
  GPHASE4(1, 1, GNOOP, GNOOP)

#pragma unroll
  for (int mf = 0; mf < MFRAG; ++mf) {
    const int row = m0 + wm * (BM / 2) + mf * 16 + quad * 4;
#pragma unroll
    for (int nf = 0; nf < NFR; ++nf) {
      const int col = n0 + wn * (BN / 4) + nf * 16 + nl;
#pragma unroll
      for (int r = 0; r < 4; ++r)
        storev(&Cm[(size_t)(row + r) * N + col], acc[mf][nf][r]);
    }
  }
}

// ---------------- V transpose: qkv V-part -> Vt[bh][d][t] ---------------------
__global__ __launch_bounds__(256) void transpose_v(const short* __restrict__ qkv,
                                                   short* __restrict__ vt) {
  __shared__ short Ls[64 * 68];
  const int bh = blockIdx.y, tb = blockIdx.x;
  const int b = bh >> 4, h = bh & 15;
  const int tid = threadIdx.x;
  const short* src = qkv + (size_t)(b * TT + tb * 64) * (3 * CC) + 2 * CC + h * 64;
#pragma unroll
  for (int i = 0; i < 2; ++i) {
    int idx = tid + i * 256;
    int tl = idx >> 3, dc = idx & 7;
    uint4 d4 = *reinterpret_cast<const uint4*>(&src[(size_t)tl * (3 * CC) + dc * 8]);
    *reinterpret_cast<uint2*>(&Ls[tl * 68 + dc * 8]) = make_uint2(d4.x, d4.y);
    *reinterpret_cast<uint2*>(&Ls[tl * 68 + dc * 8 + 4]) = make_uint2(d4.z, d4.w);
  }
  __syncthreads();
  short* dst = vt + (size_t)(bh * 64) * TT + tb * 64;
#pragma unroll
  for (int i = 0; i < 2; ++i) {
    int idx = tid + i * 256;
    int dl = idx >> 3, tc = idx & 7;
    short tmp[8];
#pragma unroll
    for (int j = 0; j < 8; ++j) tmp[j] = Ls[(tc * 8 + j) * 68 + dl];
    *reinterpret_cast<uint4*>(&dst[(size_t)dl * TT + tc * 8]) = *reinterpret_cast<uint4*>(tmp);
  }
}

// ---------------- attention compute (one 32-col half-chunk, one wave) ---------
// S roundtrip buffer: per wave 2 m-blocks x 16 rows x 16 dwords (64B rows, no
// pad). 16B-block XOR swizzle: logical dword d of row nl stored at physical
// ((d>>2) ^ ((nl>>1)&3))*4 + (d&3). Quarter-wave bank audit: b128 reads hit 8
// distinct 16B-slots (2-way, free); paired b64 writes 2-way (free).
template <bool DIAG>
__device__ __forceinline__ void attn_compute(const short* kf, const short* vf, u32* ssw,
                                             const bf16x8 (&qf)[2][2], f32x4 (&o)[2][4],
                                             int lane, int quad, int nl) {
  bf16x8 k00 = *reinterpret_cast<const bf16x8*>(&kf[0 * 512 + lane * 8]);
  bf16x8 k01 = *reinterpret_cast<const bf16x8*>(&kf[1 * 512 + lane * 8]);
  bf16x8 k10 = *reinterpret_cast<const bf16x8*>(&kf[2 * 512 + lane * 8]);
  bf16x8 k11 = *reinterpret_cast<const bf16x8*>(&kf[3 * 512 + lane * 8]);
  bf16x8 vB[4];
#pragma unroll
  for (int nb = 0; nb < 4; ++nb)
    vB[nb] = *reinterpret_cast<const bf16x8*>(&vf[nb * 512 + lane * 8]);
  const int sig = (nl >> 1) & 3;
  // logical dword pair bases: s-block0 d = quad*2, s-block1 d = 8 + quad*2
  const int plo = (((quad >> 1) ^ sig) << 2) | ((quad * 2) & 3);
  const int phi = (((2 + (quad >> 1)) ^ sig) << 2) | ((quad * 2) & 3);
  const int prd = ((quad ^ sig) << 2);  // read b128: logical dwords quad*4..+3
  {
    u32* srow = &ssw[0 * 256 + nl * 16];
    f32x4 s0 = {};
    s0 = mfma16(k00, qf[0][0], s0);
    s0 = mfma16(k01, qf[0][1], s0);
    if (DIAG) {
#pragma unroll
      for (int r = 0; r < 4; ++r) s0[r] = (quad * 4 + r <= nl) ? s0[r] : 0.0f;
    }
    *reinterpret_cast<u32x2*>(&srow[plo]) = u32x2{pack2(s0[0], s0[1]), pack2(s0[2], s0[3])};
    if (DIAG) {
      *reinterpret_cast<u32x2*>(&srow[phi]) = u32x2{0u, 0u};
    } else {
      f32x4 s1 = {};
      s1 = mfma16(k10, qf[0][0], s1);
      s1 = mfma16(k11, qf[0][1], s1);
      *reinterpret_cast<u32x2*>(&srow[phi]) = u32x2{pack2(s1[0], s1[1]), pack2(s1[2], s1[3])};
    }
  }
  {
    u32* srow = &ssw[1 * 256 + nl * 16];
    f32x4 s0 = {}, s1 = {};
    s0 = mfma16(k00, qf[1][0], s0);
    s0 = mfma16(k01, qf[1][1], s0);
    s1 = mfma16(k10, qf[1][0], s1);
    s1 = mfma16(k11, qf[1][1], s1);
    if (DIAG) {
#pragma unroll
      for (int r = 0; r < 4; ++r) s1[r] = (quad * 4 + r <= nl) ? s1[r] : 0.0f;
    }
    *reinterpret_cast<u32x2*>(&srow[plo]) = u32x2{pack2(s0[0], s0[1]), pack2(s0[2], s0[3])};
    *reinterpret_cast<u32x2*>(&srow[phi]) = u32x2{pack2(s1[0], s1[1]), pack2(s1[2], s1[3])};
  }
#pragma unroll
  for (int m = 0; m < 2; ++m) {
    bf16x8 sf = *reinterpret_cast<const bf16x8*>(&ssw[m * 256 + nl * 16 + prd]);
#pragma unroll
    for (int nb = 0; nb < 4; ++nb) o[m][nb] = mfma16(sf, vB[nb], o[m][nb]);
  }
}

// ---------------- causal masked attention (no softmax) ------------------------
// 1D grid, XCD-chunked (bh-major within XCD for K/V L2 residence). LDS = Frag
// 32 KB + Ss 8 KB = 40960 B exactly -> 4 blocks/CU (full 160 KB), 16 waves/CU.
__global__ __launch_bounds__(256, 4) void attn_kernel(const short* __restrict__ qkv,
                                                      const short* __restrict__ vt,
                                                      short* __restrict__ attnb) {
  const int gid = blockIdx.x;
  const int xcd = gid & 7, slot = gid >> 3;
  const int bh = xcd * 8 + (slot & 7);
  const int ti = 15 - (slot >> 3);  // big tiles first
  const int b = bh >> 4, h = bh & 15;
  const int T0 = ti * 128;
  const int tid = threadIdx.x;
  const int wave = tid >> 6, lane = tid & 63;
  const int quad = lane >> 4, nl = lane & 15;

  const short* qbase = qkv + (size_t)(b * TT) * (3 * CC) + h * 64;
  const short* kbase = qbase + CC;
  const short* vbase = vt + (size_t)(bh * 64) * TT;

  __shared__ __align__(16) short Frag[2][8192];  // 2 x 16 KB staged K/V frags
  __shared__ __align__(16) u32 Ss[4][512];       // per-wave S roundtrip (swizzled)
  u32* ssw = Ss[wave];

  const int tw0 = T0 + wave * 32;
  bf16x8 qf[2][2];  // Q B-frags (pre-scaled by 0.125)
#pragma unroll
  for (int m = 0; m < 2; ++m)
#pragma unroll
    for (int half = 0; half < 2; ++half)
      qf[m][half] = *reinterpret_cast<const bf16x8*>(
          &qbase[(size_t)(tw0 + m * 16 + nl) * (3 * CC) + half * 32 + quad * 8]);

  f32x4 o[2][4] = {};

  const short* ksrc = kbase + (size_t)(wave * 16 + nl) * (3 * CC) + quad * 8;
  const int sp_w = wave >> 1, nb0 = (wave & 1) * 2;
  const short* vsrc0 = vbase + (size_t)((nb0 + 0) * 16 + nl) * TT + sp_w * 32 + quad * 8;
  const short* vsrc1 = vbase + (size_t)((nb0 + 1) * 16 + nl) * TT + sp_w * 32 + quad * 8;

  auto stage = [&](short* fb, int c) {
    const size_t koff = (size_t)(c * 64) * (3 * CC);
#if HAVE_GLD_LDS
    gld_lds16(ksrc + koff, &fb[(2 * wave) * 512]);
    gld_lds16(ksrc + koff + 32, &fb[(2 * wave + 1) * 512]);
    gld_lds16(vsrc0 + c * 64, &fb[4096 + (2 * wave) * 512]);
    gld_lds16(vsrc1 + c * 64, &fb[4096 + (2 * wave + 1) * 512]);
#else
    *reinterpret_cast<uint4*>(&fb[(2 * wave) * 512 + lane * 8]) =
        *reinterpret_cast<const uint4*>(ksrc + koff);
    *reinterpret_cast<uint4*>(&fb[(2 * wave + 1) * 512 + lane * 8]) =
        *reinterpret_cast<const uint4*>(ksrc + koff + 32);
    *reinterpret_cast<uint4*>(&fb[4096 + (2 * wave) * 512 + lane * 8]) =
        *reinterpret_cast<const uint4*>(vsrc0 + c * 64);
    *reinterpret_cast<uint4*>(&fb[4096 + (2 * wave + 1) * 512 + lane * 8]) =
        *reinterpret_cast<const uint4*>(vsrc1 + c * 64);
#endif
  };

  const int nch = 2 * ti + 2;     // 64-col chunks
  const int cd = 4 * ti + wave;   // this wave's diagonal 32-chunk index

  stage(Frag[0], 0);
  for (int c = 0; c < nch; ++c) {
    __syncthreads();  // compiler vmcnt(0) here drains stage(c); buf[c&1] ready
    if (c + 1 < nch) stage(Frag[(c + 1) & 1], c + 1);  // overlaps compute below
    const short* fb = Frag[c & 1];
    const int c0 = 2 * c, c1 = 2 * c + 1;
    if (c0 < cd)
      attn_compute<false>(fb, fb + 4096, ssw, qf, o, lane, quad, nl);
    else if (c0 == cd)
      attn_compute<true>(fb, fb + 4096, ssw, qf, o, lane, quad, nl);
    if (c1 < cd)
      attn_compute<false>(fb + 2048, fb + 4096 + 2048, ssw, qf, o, lane, quad, nl);
    else if (c1 == cd)
      attn_compute<true>(fb + 2048, fb + 4096 + 2048, ssw, qf, o, lane, quad, nl);
  }

  // epilogue: O C-layout row=t(quad*4+r), col=d(nl) -> attnb[b][t][h*64+d]
#pragma unroll
  for (int m = 0; m < 2; ++m)
#pragma unroll
    for (int nb = 0; nb < 4; ++nb)
#pragma unroll
      for (int r = 0; r < 4; ++r) {
        int t = tw0 + m * 16 + quad * 4 + r;
        attnb[(size_t)(b * TT + t) * CC + h * 64 + nb * 16 + nl] = f2bf(o[m][nb][r]);
      }
}

extern "C" void kernel_launch(void* const* d_in, const int* in_sizes, int n_in,
                              void* d_out, int out_size, void* d_ws, size_t ws_size,
                              hipStream_t stream) {
  const float* x = (const float*)d_in[0];      // [4,2048,1024]
  const float* wqkv = (const float*)d_in[1];   // [3072,1024]
  const float* wout = (const float*)d_in[2];   // [1024,1024]
  float* out = (float*)d_out;                  // [4,2048,1024] fp32

  char* ws = (char*)d_ws;
  short* xb    = (short*)(ws);                  // 16.78 MB
  short* wqkvb = (short*)(ws + 16777216);       //  6.29 MB
  short* woutb = (short*)(ws + 23068672);       //  2.10 MB
  short* qkvb  = (short*)(ws + 25165824);       // 50.33 MB
  short* attnb = (short*)(ws + 75497472);       // 16.78 MB  (total 92.27 MB)
  short* vt    = xb;  // xb dead after QKV GEMM

  static bool inited = false;
  if (!inited) {  // dynamic LDS opt-in (not a stream op; capture-safe)
    (void)hipFuncSetAttribute(reinterpret_cast<const void*>(&gemm4p<short, 3072, 1024, 128, 384>),
                              hipFuncAttributeMaxDynamicSharedMemorySize, 131072);
    (void)hipFuncSetAttribute(reinterpret_cast<const void*>(&gemm4p<float, 1024, 1024, 128, 256>),
                              hipFuncAttributeMaxDynamicSharedMemorySize, 98304);
    inited = true;
  }

  cvt_all<<<12288, 256, 0, stream>>>(x, wqkv, wout, xb);

  // QKV: M=8192 N=3072, BM=128 BN=384 -> 64x8 = 512 blocks (2 exact rounds)
  gemm4p<short, 3072, 1024, 128, 384><<<512, 512, 131072, stream>>>(xb, wqkvb, qkvb);

  transpose_v<<<dim3(32, 64), 256, 0, stream>>>(qkvb, vt);

  attn_kernel<<<1024, 256, 0, stream>>>(qkvb, vt, attnb);

  // out-proj: M=8192 N=1024, BM=128 BN=256 -> 64x4 = 256 blocks (1 exact round)
  gemm4p<float, 1024, 1024, 128, 256><<<256, 512, 98304, stream>>>(attnb, woutb, out);
}

// Round 9
// 226.907 us; speedup vs baseline: 1.0117x; 1.0117x over previous
//
#include <hip/hip_runtime.h>

#define TT 2048
#define CC 1024

typedef __attribute__((ext_vector_type(8))) __bf16 bf16x8;
typedef __attribute__((ext_vector_type(4))) float f32x4;
typedef unsigned int u32;
typedef __attribute__((ext_vector_type(2))) u32 u32x2;

__device__ __forceinline__ short f2bf(float f) {
  u32 u = __float_as_uint(f);
  u += 0x7fffu + ((u >> 16) & 1u);  // RTNE
  return (short)(u >> 16);
}

#if __has_builtin(__builtin_amdgcn_cvt_pk_bf16_f32)
__device__ __forceinline__ u32 pack2(float a, float b) {
  auto v = __builtin_amdgcn_cvt_pk_bf16_f32(a, b);
  return __builtin_bit_cast(u32, v);
}
#else
__device__ __forceinline__ u32 pack2(float a, float b) {
  u32 ua = __float_as_uint(a), ub = __float_as_uint(b);
  ua += 0x7fffu + ((ua >> 16) & 1u);
  ub += 0x7fffu + ((ub >> 16) & 1u);
  return (ua >> 16) | (ub & 0xffff0000u);
}
#endif

// ---------------- fused fp32 -> bf16 cast (x | wqkv(Q scaled) | wout) ---------
__global__ __launch_bounds__(256) void cvt_all(const float* __restrict__ x,
                                               const float* __restrict__ wqkv,
                                               const float* __restrict__ wout,
                                               short* __restrict__ dst) {
  int i = blockIdx.x * blockDim.x + threadIdx.x;  // float4 index, < 3145728
  const float* src;
  float sc = 1.0f;
  if (i < 2097152) {
    src = x + (size_t)i * 4;
  } else if (i < 2883584) {
    int j = i - 2097152;
    src = wqkv + (size_t)j * 4;
    if (j < 262144) sc = 0.125f;  // Q block: fold attention scale (exact pow2)
  } else {
    src = wout + (size_t)(i - 2883584) * 4;
  }
  float4 f = *reinterpret_cast<const float4*>(src);
  short4 s;
  s.x = f2bf(f.x * sc); s.y = f2bf(f.y * sc); s.z = f2bf(f.z * sc); s.w = f2bf(f.w * sc);
  reinterpret_cast<short4*>(dst)[i] = s;
}

__device__ __forceinline__ void storev(float* p, float v) { *p = v; }
__device__ __forceinline__ void storev(short* p, float v) { *p = f2bf(v); }

#if __has_builtin(__builtin_amdgcn_global_load_lds)
#define HAVE_GLD_LDS 1
__device__ __forceinline__ void gld_lds16(const short* g, short* l) {
  __builtin_amdgcn_global_load_lds((const __attribute__((address_space(1))) u32*)g,
                                   (__attribute__((address_space(3))) u32*)l, 16, 0, 0);
}
#endif

__device__ __forceinline__ f32x4 mfma16(bf16x8 a, bf16x8 b, f32x4 c) {
  return __builtin_amdgcn_mfma_f32_16x16x32_bf16(a, b, c, 0, 0, 0);
}

template <int NN>
__device__ __forceinline__ void waitvm() {
  if constexpr (NN == 0) asm volatile("s_waitcnt vmcnt(0)" ::: "memory");
  else if constexpr (NN == 3) asm volatile("s_waitcnt vmcnt(3)" ::: "memory");
  else if constexpr (NN == 4) asm volatile("s_waitcnt vmcnt(4)" ::: "memory");
  else if constexpr (NN == 6) asm volatile("s_waitcnt vmcnt(6)" ::: "memory");
  else if constexpr (NN == 8) asm volatile("s_waitcnt vmcnt(8)" ::: "memory");
}

// =================== C[M,N] = A[M,K] * B[N,K]^T, 128xBN 4-phase ===============
// K-loop unchanged from round 4. SPLITV variant (QKV gemm): output cols <2048
// (Q|K) go to a PACKED [8192][2048] qk buffer; cols >=2048 (V) are written
// DIRECTLY TRANSPOSED to vt[bh*64+d][t] — lane's 4 acc rows are 4 consecutive
// t at fixed feature -> one aligned 8B short4 store. Kills the transpose_v
// kernel (saves 33.6 MB of traffic + a launch). Branch on col>=2048 is
// wave-uniform (all col-blocks 16-aligned). vt is a separate region (no xb
// aliasing -> safe to write while other blocks stream A).
#define GNOOP ((void)0)
#define GPHASE4(DB, KS, STG, SYNC)                         \
  {                                                        \
    bf16x8 af[MFRAG], bfr[NFR];                            \
    ldA(af, DB, KS);                                       \
    ldB(bfr, DB, KS);                                      \
    STG;                                                   \
    __builtin_amdgcn_s_setprio(1);                         \
    mmaAll(af, bfr);                                       \
    __builtin_amdgcn_s_setprio(0);                         \
    asm volatile("s_waitcnt lgkmcnt(0)" ::: "memory");     \
    SYNC;                                                  \
    __builtin_amdgcn_s_barrier();                          \
  }

template <typename OutT, int N, int K, int BM, int BN, bool SPLITV>
__global__ __launch_bounds__(512, 2) void gemm4p(const short* __restrict__ A,
                                                 const short* __restrict__ B,
                                                 OutT* __restrict__ Cm,
                                                 short* __restrict__ Vt) {
  constexpr int MFRAG = BM / 32;
  constexpr int NFR = BN / 64;
  constexpr int AGLD = BM / 128;
  constexpr int BGLD = BN / 128;
  constexpr int GPP = AGLD + BGLD;
  constexpr int SYNCN = 2 * GPP;
  constexpr int NT = K / 64, NITER = NT / 2;
  constexpr int DBS = 64 * (BM + BN);
  constexpr int TMX = (8192 / BM) / 8;
  constexpr int CSTRIDE = SPLITV ? 2048 : N;  // packed QK row stride
  extern __shared__ short lds[];
  const int tid = threadIdx.x;
  const int wave = tid >> 6, lane = tid & 63;
  const int quad = lane >> 4, nl = lane & 15;
  const int wm = wave >> 2, wn = wave & 3;

  const int id = blockIdx.x;
  const int xcd = id & 7, slot = id >> 3;
  const int mt = xcd * TMX + (slot % TMX);
  const int nt = slot / TMX;
  const int m0 = mt * BM, n0 = nt * BN;

  const int srow = lane >> 2;
  const int sperm = ((lane & 3) ^ ((lane >> 3) & 3)) * 8;
  const short* pA = A + (size_t)(m0 + wave * (BM / 8) + srow) * K + sperm;
  const short* pB = B + (size_t)(n0 + wave * (BN / 8) + srow) * K + sperm;

  const int perm = (quad ^ ((nl >> 1) & 3)) * 8;

  f32x4 acc[MFRAG][NFR] = {};

  auto stageA = [&](int db, int ks, int t) {
    const short* s = pA + (size_t)t * 64 + ks * 32;
    short* d = lds + db * DBS + ks * (BM * 32) + wave * (BM * 4);
#pragma unroll
    for (int j = 0; j < AGLD; ++j) {
#if HAVE_GLD_LDS
      gld_lds16(s + (size_t)j * 16 * K, d + j * 512);
#else
      *reinterpret_cast<uint4*>(d + j * 512 + lane * 8) =
          *reinterpret_cast<const uint4*>(s + (size_t)j * 16 * K);
#endif
    }
  };
  auto stageB = [&](int db, int ks, int t) {
    const short* s = pB + (size_t)t * 64 + ks * 32;
    short* d = lds + db * DBS + BM * 64 + ks * (BN * 32) + wave * (BN * 4);
#pragma unroll
    for (int j = 0; j < BGLD; ++j) {
#if HAVE_GLD_LDS
      gld_lds16(s + (size_t)j * 16 * K, d + j * 512);
#else
      *reinterpret_cast<uint4*>(d + j * 512 + lane * 8) =
          *reinterpret_cast<const uint4*>(s + (size_t)j * 16 * K);
#endif
    }
  };
  auto stage = [&](int db, int ks, int t) { stageA(db, ks, t); stageB(db, ks, t); };

  auto ldA = [&](bf16x8 (&af)[MFRAG], int db, int ks) {
#pragma unroll
    for (int mf = 0; mf < MFRAG; ++mf)
      af[mf] = *reinterpret_cast<const bf16x8*>(
          &lds[db * DBS + ks * (BM * 32) + (wm * (BM / 2) + mf * 16 + nl) * 32 + perm]);
  };
  auto ldB = [&](bf16x8 (&bfr)[NFR], int db, int ks) {
#pragma unroll
    for (int nf = 0; nf < NFR; ++nf)
      bfr[nf] = *reinterpret_cast<const bf16x8*>(
          &lds[db * DBS + BM * 64 + ks * (BN * 32) + (wn * (BN / 4) + nf * 16 + nl) * 32 + perm]);
  };
  auto mmaAll = [&](const bf16x8 (&af)[MFRAG], const bf16x8 (&bfr)[NFR]) {
#pragma unroll
    for (int mf = 0; mf < MFRAG; ++mf)
#pragma unroll
      for (int nf = 0; nf < NFR; ++nf)
        acc[mf][nf] = mfma16(af[mf], bfr[nf], acc[mf][nf]);
  };

  stage(0, 0, 0); stage(0, 1, 0); stage(1, 0, 1);
  waitvm<SYNCN>();
  __builtin_amdgcn_s_barrier();

  for (int i = 0; i < NITER - 1; ++i) {
    GPHASE4(0, 0, stage(1, 1, 2 * i + 1), waitvm<SYNCN>())
    GPHASE4(0, 1, stage(0, 0, 2 * i + 2), waitvm<SYNCN>())
    GPHASE4(1, 0, stage(0, 1, 2 * i + 2), waitvm<SYNCN>())
    GPHASE4(1, 1, stage(1, 0, 2 * i + 3), waitvm<SYNCN>())
  }
  GPHASE4(0, 0, stage(1, 1, NT - 1), waitvm<SYNCN>())
  GPHASE4(0, 1, GNOOP, waitvm<GPP>())
  GPHASE4(1, 0, GNOOP, waitvm<0>())
  GPHASE4(1, 1, GNOOP, GNOOP)

#pragma unroll
  for (int mf = 0; mf < MFRAG; ++mf) {
    const int row = m0 + wm * (BM / 2) + mf * 16 + quad * 4;
#pragma unroll
    for (int nf = 0; nf < NFR; ++nf) {
      const int col = n0 + wn * (BN / 4) + nf * 16 + nl;
      bool isv = false;
      if constexpr (SPLITV) isv = (col >= 2048);  // wave-uniform per (mf,nf)
      if (isv) {
        const int feat = col - 2048;              // h*64+d
        const int b = row >> 11, t = row & 2047;  // t = quad*4.., 4-consecutive
        short4 v4;
        v4.x = f2bf(acc[mf][nf][0]); v4.y = f2bf(acc[mf][nf][1]);
        v4.z = f2bf(acc[mf][nf][2]); v4.w = f2bf(acc[mf][nf][3]);
        *reinterpret_cast<short4*>(&Vt[((size_t)(b << 10) + feat) * 2048 + t]) = v4;
      } else {
#pragma unroll
        for (int r = 0; r < 4; ++r)
          storev(&Cm[(size_t)(row + r) * CSTRIDE + col], acc[mf][nf][r]);
      }
    }
  }
}

// ---------------- attention compute (one 32-col half-chunk, one wave) ---------
// S roundtrip buffer: per wave 2 m-blocks x 16 rows x 16 dwords (64B rows, no
// pad). 16B-block XOR swizzle: logical dword d of row nl stored at physical
// ((d>>2) ^ ((nl>>1)&3))*4 + (d&3). Quarter-wave bank audit: b128 reads hit 8
// distinct 16B-slots (2-way, free); paired b64 writes 2-way (free).
template <bool DIAG>
__device__ __forceinline__ void attn_compute(const short* kf, const short* vf, u32* ssw,
                                             const bf16x8 (&qf)[2][2], f32x4 (&o)[2][4],
                                             int lane, int quad, int nl) {
  bf16x8 k00 = *reinterpret_cast<const bf16x8*>(&kf[0 * 512 + lane * 8]);
  bf16x8 k01 = *reinterpret_cast<const bf16x8*>(&kf[1 * 512 + lane * 8]);
  bf16x8 k10 = *reinterpret_cast<const bf16x8*>(&kf[2 * 512 + lane * 8]);
  bf16x8 k11 = *reinterpret_cast<const bf16x8*>(&kf[3 * 512 + lane * 8]);
  bf16x8 vB[4];
#pragma unroll
  for (int nb = 0; nb < 4; ++nb)
    vB[nb] = *reinterpret_cast<const bf16x8*>(&vf[nb * 512 + lane * 8]);
  const int sig = (nl >> 1) & 3;
  const int plo = (((quad >> 1) ^ sig) << 2) | ((quad * 2) & 3);
  const int phi = (((2 + (quad >> 1)) ^ sig) << 2) | ((quad * 2) & 3);
  const int prd = ((quad ^ sig) << 2);  // read b128: logical dwords quad*4..+3
  {
    u32* srow = &ssw[0 * 256 + nl * 16];
    f32x4 s0 = {};
    s0 = mfma16(k00, qf[0][0], s0);
    s0 = mfma16(k01, qf[0][1], s0);
    if (DIAG) {
#pragma unroll
      for (int r = 0; r < 4; ++r) s0[r] = (quad * 4 + r <= nl) ? s0[r] : 0.0f;
    }
    *reinterpret_cast<u32x2*>(&srow[plo]) = u32x2{pack2(s0[0], s0[1]), pack2(s0[2], s0[3])};
    if (DIAG) {
      *reinterpret_cast<u32x2*>(&srow[phi]) = u32x2{0u, 0u};
    } else {
      f32x4 s1 = {};
      s1 = mfma16(k10, qf[0][0], s1);
      s1 = mfma16(k11, qf[0][1], s1);
      *reinterpret_cast<u32x2*>(&srow[phi]) = u32x2{pack2(s1[0], s1[1]), pack2(s1[2], s1[3])};
    }
  }
  {
    u32* srow = &ssw[1 * 256 + nl * 16];
    f32x4 s0 = {}, s1 = {};
    s0 = mfma16(k00, qf[1][0], s0);
    s0 = mfma16(k01, qf[1][1], s0);
    s1 = mfma16(k10, qf[1][0], s1);
    s1 = mfma16(k11, qf[1][1], s1);
    if (DIAG) {
#pragma unroll
      for (int r = 0; r < 4; ++r) s1[r] = (quad * 4 + r <= nl) ? s1[r] : 0.0f;
    }
    *reinterpret_cast<u32x2*>(&srow[plo]) = u32x2{pack2(s0[0], s0[1]), pack2(s0[2], s0[3])};
    *reinterpret_cast<u32x2*>(&srow[phi]) = u32x2{pack2(s1[0], s1[1]), pack2(s1[2], s1[3])};
  }
#pragma unroll
  for (int m = 0; m < 2; ++m) {
    bf16x8 sf = *reinterpret_cast<const bf16x8*>(&ssw[m * 256 + nl * 16 + prd]);
#pragma unroll
    for (int nb = 0; nb < 4; ++nb) o[m][nb] = mfma16(sf, vB[nb], o[m][nb]);
  }
}

// ---------------- causal masked attention (no softmax) ------------------------
// Inputs: qk packed [8192][2048] (Q cols 0..1023 | K cols 1024..2047), vt
// [bh*64+d][t]. 1D grid, XCD-chunked (bh-major within XCD for K/V L2
// residence). LDS = 32 KB Frag + 8 KB Ss = 40960 B -> 4 blocks/CU.
__global__ __launch_bounds__(256, 4) void attn_kernel(const short* __restrict__ qk,
                                                      const short* __restrict__ vt,
                                                      short* __restrict__ attnb) {
  const int gid = blockIdx.x;
  const int xcd = gid & 7, slot = gid >> 3;
  const int bh = xcd * 8 + (slot & 7);
  const int ti = 15 - (slot >> 3);  // big tiles first
  const int b = bh >> 4, h = bh & 15;
  const int T0 = ti * 128;
  const int tid = threadIdx.x;
  const int wave = tid >> 6, lane = tid & 63;
  const int quad = lane >> 4, nl = lane & 15;

  const short* qbase = qk + (size_t)(b * TT) * (2 * CC) + h * 64;
  const short* kbase = qbase + CC;  // K cols start at 1024
  const short* vbase = vt + (size_t)(bh * 64) * TT;

  __shared__ __align__(16) short Frag[2][8192];  // 2 x 16 KB staged K/V frags
  __shared__ __align__(16) u32 Ss[4][512];       // per-wave S roundtrip (swizzled)
  u32* ssw = Ss[wave];

  const int tw0 = T0 + wave * 32;
  bf16x8 qf[2][2];  // Q B-frags (pre-scaled by 0.125)
#pragma unroll
  for (int m = 0; m < 2; ++m)
#pragma unroll
    for (int half = 0; half < 2; ++half)
      qf[m][half] = *reinterpret_cast<const bf16x8*>(
          &qbase[(size_t)(tw0 + m * 16 + nl) * (2 * CC) + half * 32 + quad * 8]);

  f32x4 o[2][4] = {};

  const short* ksrc = kbase + (size_t)(wave * 16 + nl) * (2 * CC) + quad * 8;
  const int sp_w = wave >> 1, nb0 = (wave & 1) * 2;
  const short* vsrc0 = vbase + (size_t)((nb0 + 0) * 16 + nl) * TT + sp_w * 32 + quad * 8;
  const short* vsrc1 = vbase + (size_t)((nb0 + 1) * 16 + nl) * TT + sp_w * 32 + quad * 8;

  auto stage = [&](short* fb, int c) {
    const size_t koff = (size_t)(c * 64) * (2 * CC);
#if HAVE_GLD_LDS
    gld_lds16(ksrc + koff, &fb[(2 * wave) * 512]);
    gld_lds16(ksrc + koff + 32, &fb[(2 * wave + 1) * 512]);
    gld_lds16(vsrc0 + c * 64, &fb[4096 + (2 * wave) * 512]);
    gld_lds16(vsrc1 + c * 64, &fb[4096 + (2 * wave + 1) * 512]);
#else
    *reinterpret_cast<uint4*>(&fb[(2 * wave) * 512 + lane * 8]) =
        *reinterpret_cast<const uint4*>(ksrc + koff);
    *reinterpret_cast<uint4*>(&fb[(2 * wave + 1) * 512 + lane * 8]) =
        *reinterpret_cast<const uint4*>(ksrc + koff + 32);
    *reinterpret_cast<uint4*>(&fb[4096 + (2 * wave) * 512 + lane * 8]) =
        *reinterpret_cast<const uint4*>(vsrc0 + c * 64);
    *reinterpret_cast<uint4*>(&fb[4096 + (2 * wave + 1) * 512 + lane * 8]) =
        *reinterpret_cast<const uint4*>(vsrc1 + c * 64);
#endif
  };

  const int nch = 2 * ti + 2;     // 64-col chunks
  const int cd = 4 * ti + wave;   // this wave's diagonal 32-chunk index

  stage(Frag[0], 0);
  for (int c = 0; c < nch; ++c) {
    __syncthreads();  // compiler vmcnt(0) here drains stage(c); buf[c&1] ready
    if (c + 1 < nch) stage(Frag[(c + 1) & 1], c + 1);  // overlaps compute below
    const short* fb = Frag[c & 1];
    const int c0 = 2 * c, c1 = 2 * c + 1;
    if (c0 < cd)
      attn_compute<false>(fb, fb + 4096, ssw, qf, o, lane, quad, nl);
    else if (c0 == cd)
      attn_compute<true>(fb, fb + 4096, ssw, qf, o, lane, quad, nl);
    if (c1 < cd)
      attn_compute<false>(fb + 2048, fb + 4096 + 2048, ssw, qf, o, lane, quad, nl);
    else if (c1 == cd)
      attn_compute<true>(fb + 2048, fb + 4096 + 2048, ssw, qf, o, lane, quad, nl);
  }

  // epilogue: O C-layout row=t(quad*4+r), col=d(nl) -> attnb[b][t][h*64+d]
#pragma unroll
  for (int m = 0; m < 2; ++m)
#pragma unroll
    for (int nb = 0; nb < 4; ++nb)
#pragma unroll
      for (int r = 0; r < 4; ++r) {
        int t = tw0 + m * 16 + quad * 4 + r;
        attnb[(size_t)(b * TT + t) * CC + h * 64 + nb * 16 + nl] = f2bf(o[m][nb][r]);
      }
}

extern "C" void kernel_launch(void* const* d_in, const int* in_sizes, int n_in,
                              void* d_out, int out_size, void* d_ws, size_t ws_size,
                              hipStream_t stream) {
  const float* x = (const float*)d_in[0];      // [4,2048,1024]
  const float* wqkv = (const float*)d_in[1];   // [3072,1024]
  const float* wout = (const float*)d_in[2];   // [1024,1024]
  float* out = (float*)d_out;                  // [4,2048,1024] fp32

  char* ws = (char*)d_ws;
  short* xb    = (short*)(ws);                  // 16.78 MB
  short* wqkvb = (short*)(ws + 16777216);       //  6.29 MB
  short* woutb = (short*)(ws + 23068672);       //  2.10 MB
  short* qk    = (short*)(ws + 25165824);       // 33.55 MB packed [8192][2048]
  short* vt    = (short*)(ws + 58720256);       // 16.78 MB [bh*64+d][t]
  short* attnb = (short*)(ws + 75497472);       // 16.78 MB  (total 92.27 MB)

  static bool inited = false;
  if (!inited) {  // dynamic LDS opt-in (not a stream op; capture-safe)
    (void)hipFuncSetAttribute(
        reinterpret_cast<const void*>(&gemm4p<short, 3072, 1024, 128, 384, true>),
        hipFuncAttributeMaxDynamicSharedMemorySize, 131072);
    (void)hipFuncSetAttribute(
        reinterpret_cast<const void*>(&gemm4p<float, 1024, 1024, 128, 256, false>),
        hipFuncAttributeMaxDynamicSharedMemorySize, 98304);
    inited = true;
  }

  cvt_all<<<12288, 256, 0, stream>>>(x, wqkv, wout, xb);

  // QKV: M=8192 N=3072, BM=128 BN=384 -> 64x8 = 512 blocks (2 exact rounds).
  // Q|K cols -> packed qk[8192][2048]; V cols -> vt transposed (fused).
  gemm4p<short, 3072, 1024, 128, 384, true><<<512, 512, 131072, stream>>>(xb, wqkvb, qk, vt);

  attn_kernel<<<1024, 256, 0, stream>>>(qk, vt, attnb);

  // out-proj: M=8192 N=1024, BM=128 BN=256 -> 64x4 = 256 blocks (1 exact round)
  gemm4p<float, 1024, 1024, 128, 256, false><<<256, 512, 98304, stream>>>(attnb, woutb, out,
                                                                          nullptr);
}